// Round 2
// baseline (28207.651 us; speedup 1.0000x reference)
//
#include <hip/hip_runtime.h>
#include <hip/hip_bf16.h>

#define BSZ 512
#define SEQ 64
#define IDIM 300
#define IPAD 304
#define HDIM 1024
#define G4 4096
#define BH (BSZ*HDIM)   // 524288

__device__ __forceinline__ float sigmoidf_(float x){ return 1.f/(1.f+__expf(-x)); }

// ---------------- setup kernels ----------------
__global__ void embed_gather_k(const int* __restrict__ x, const float* __restrict__ embed,
                               float* __restrict__ xs){
    int t = blockIdx.x;   // SEQ
    int b = blockIdx.y;   // BSZ
    int ix = x[b*SEQ + t];
    const float* src = embed + (size_t)ix * IDIM;
    float* dst = xs + ((size_t)t*BSZ + b) * IPAD;
    for (int k = threadIdx.x; k < IPAD; k += 64)
        dst[k] = (k < IDIM) ? src[k] : 0.f;
}

__global__ void pad_w_k(const float* __restrict__ We, const float* __restrict__ Wd,
                        float* __restrict__ Pe, float* __restrict__ Pd){
    int n = blockIdx.x;                 // 4096
    const float* src = blockIdx.y ? Wd : We;
    float* dst = blockIdx.y ? Pd : Pe;
    for (int k = threadIdx.x; k < IPAD; k += 64)
        dst[(size_t)n*IPAD + k] = (k < IDIM) ? src[(size_t)n*IDIM + k] : 0.f;
}

__global__ void bias_comb_k(const float* __restrict__ a, const float* __restrict__ b2,
                            const float* __restrict__ c2, const float* __restrict__ d2,
                            float* __restrict__ be, float* __restrict__ bd){
    int i = blockIdx.x*256 + threadIdx.x;   // 8192 threads
    if (i < G4) be[i] = a[i] + b2[i];
    else { int j = i - G4; bd[j] = c2[j] + d2[j]; }
}

__global__ void zero_hc_k(float* __restrict__ h, float* __restrict__ c){
    int idx = blockIdx.x*256 + threadIdx.x;
    h[idx] = 0.f; c[idx] = 0.f;
}

// ---------------- fused gate GEMM: G = bias + A1@B1^T + A2@B2^T ----------------
// A1:[512][K1], B1:[4096][K1], A2:[512][K2], B2:[4096][K2], G:[512][4096]
#define BM 64
#define BN 128
#define BK 16
__global__ __launch_bounds__(256) void lstm_gemm_k(
    const float* __restrict__ A1, int K1, const float* __restrict__ B1,
    const float* __restrict__ A2, int K2, const float* __restrict__ B2,
    const float* __restrict__ bias, float* __restrict__ Gm)
{
    __shared__ __align__(16) float As[BK][72];
    __shared__ __align__(16) float Bs[BK][136];
    const int tid = threadIdx.x;
    const int col0 = blockIdx.x * BN;
    const int row0 = blockIdx.y * BM;
    const int ty = tid >> 4, tx = tid & 15;
    float acc[4][8];
    #pragma unroll
    for (int i=0;i<4;i++)
        #pragma unroll
        for (int j=0;j<8;j++) acc[i][j]=0.f;

    for (int ph = 0; ph < 2; ++ph){
        const float* A  = ph ? A2 : A1;
        const float* Bm = ph ? B2 : B1;
        const int K = ph ? K2 : K1;
        for (int k0 = 0; k0 < K; k0 += BK){
            {   // A tile: 64 rows x 16 k (transposed into LDS), float4 loads
                int ar = tid >> 2, ak = (tid & 3) * 4;
                const float4 v = *reinterpret_cast<const float4*>(&A[(size_t)(row0+ar)*K + k0 + ak]);
                As[ak+0][ar]=v.x; As[ak+1][ar]=v.y; As[ak+2][ar]=v.z; As[ak+3][ar]=v.w;
            }
            #pragma unroll
            for (int r = 0; r < 2; ++r){   // B tile: 128 rows x 16 k
                int l = tid + r*256;
                int br = l >> 2, bk = (l & 3) * 4;
                const float4 v = *reinterpret_cast<const float4*>(&Bm[(size_t)(col0+br)*K + k0 + bk]);
                Bs[bk+0][br]=v.x; Bs[bk+1][br]=v.y; Bs[bk+2][br]=v.z; Bs[bk+3][br]=v.w;
            }
            __syncthreads();
            #pragma unroll
            for (int kk = 0; kk < BK; ++kk){
                float4 a  = *reinterpret_cast<const float4*>(&As[kk][ty*4]);
                float4 b0 = *reinterpret_cast<const float4*>(&Bs[kk][tx*8]);
                float4 b1 = *reinterpret_cast<const float4*>(&Bs[kk][tx*8+4]);
                float av[4]={a.x,a.y,a.z,a.w};
                float bv[8]={b0.x,b0.y,b0.z,b0.w,b1.x,b1.y,b1.z,b1.w};
                #pragma unroll
                for (int i=0;i<4;i++)
                    #pragma unroll
                    for (int j=0;j<8;j++)
                        acc[i][j] += av[i]*bv[j];
            }
            __syncthreads();
        }
    }
    #pragma unroll
    for (int i=0;i<4;i++){
        int gr = row0 + ty*4 + i;
        #pragma unroll
        for (int j=0;j<8;j++){
            int gc = col0 + tx*8 + j;
            Gm[(size_t)gr*G4 + gc] = acc[i][j] + bias[gc];
        }
    }
}

// ---------------- LSTM pointwise gates ----------------
// mode 0: extraOut[idx]=h  (encoder fwd -> enc_out)
// mode 1: extraOut[idx]=0.5*(extraIn[idx]+h)  (encoder bwd combine, in place)
// mode 2: no extra write (decoder)
__global__ __launch_bounds__(256) void lstm_gates_k(
    const float* __restrict__ Gm, float* __restrict__ c, float* __restrict__ h,
    const float* __restrict__ extraIn, float* __restrict__ extraOut, int mode)
{
    int idx = blockIdx.x*256 + threadIdx.x;          // [0, 512*1024)
    int b = idx >> 10, j = idx & 1023;
    const float* g = Gm + (size_t)b*G4;
    float gi = g[j], gf = g[j+HDIM], gg = g[j+2*HDIM], go = g[j+3*HDIM];
    float cc = sigmoidf_(gf)*c[idx] + sigmoidf_(gi)*tanhf(gg);
    float hh = sigmoidf_(go)*tanhf(cc);
    c[idx] = cc; h[idx] = hh;
    if (mode == 0)      extraOut[idx] = hh;
    else if (mode == 1) extraOut[idx] = 0.5f*(extraIn[idx] + hh);
}

// ---------------- attention ----------------
__global__ __launch_bounds__(256) void attn_part_k(
    const float* __restrict__ h, const float* __restrict__ enc, float* __restrict__ part)
{
    int ch = blockIdx.x;   // 64 chunks of 8192
    int s  = blockIdx.y;   // 64
    const float* e  = enc + (size_t)s*BH + (size_t)ch*8192;
    const float* hp = h + (size_t)ch*8192;
    float sum = 0.f;
    for (int i = threadIdx.x; i < 8192; i += 256)
        sum += hp[i] * e[i];
    #pragma unroll
    for (int m = 32; m >= 1; m >>= 1) sum += __shfl_xor(sum, m);
    __shared__ float red[4];
    int lane = threadIdx.x & 63, wv = threadIdx.x >> 6;
    if (lane == 0) red[wv] = sum;
    __syncthreads();
    if (threadIdx.x == 0) part[s*64 + ch] = red[0]+red[1]+red[2]+red[3];
}

__global__ void attn_softmax_k(const float* __restrict__ part, float* __restrict__ w){
    int s = threadIdx.x;   // 64 lanes = 64 timesteps
    float tot = 0.f;
    for (int ch = 0; ch < 64; ++ch) tot += part[s*64 + ch];
    float m = tot;
    #pragma unroll
    for (int msk = 32; msk >= 1; msk >>= 1) m = fmaxf(m, __shfl_xor(m, msk));
    float e = __expf(tot - m);
    float sm = e;
    #pragma unroll
    for (int msk = 32; msk >= 1; msk >>= 1) sm += __shfl_xor(sm, msk);
    w[s] = e / sm;
}

__global__ __launch_bounds__(256) void attn_apply_k(
    const float* __restrict__ h, const float* __restrict__ w,
    const float* __restrict__ enc, float* __restrict__ hat)
{
    __shared__ float wl[64];
    if (threadIdx.x < 64) wl[threadIdx.x] = w[threadIdx.x];
    __syncthreads();
    size_t idx = (size_t)blockIdx.x*256 + threadIdx.x;
    float v = h[idx];
    #pragma unroll 8
    for (int s = 0; s < SEQ; ++s)
        v += wl[s] * enc[(size_t)s*BH + idx];
    hat[idx] = v;
}

// ---------------- final linear + mask, float32 out ----------------
__global__ void dec_linear_k(const float* __restrict__ h, const float* __restrict__ Wl,
                             const float* __restrict__ bl, const int* __restrict__ len,
                             float* __restrict__ out, int t)
{
    int b = blockIdx.x, lane = threadIdx.x;     // 512 blocks x 64 lanes
    const float* hb = h + (size_t)b*HDIM;
    float s0 = 0.f, s1 = 0.f;
    for (int j = lane; j < HDIM; j += 64){
        float v = hb[j];
        s0 += v * Wl[j];
        s1 += v * Wl[HDIM + j];
    }
    #pragma unroll
    for (int m = 32; m >= 1; m >>= 1){ s0 += __shfl_xor(s0, m); s1 += __shfl_xor(s1, m); }
    if (lane == 0){
        bool valid = t < len[b];
        float o0 = valid ? (s0 + bl[0]) : 1.0f;
        float o1 = valid ? (s1 + bl[1]) : 0.0f;
        size_t r = ((size_t)b*SEQ + t)*2;
        out[r]   = o0;
        out[r+1] = o1;
    }
}

// ---------------- launch ----------------
extern "C" void kernel_launch(void* const* d_in, const int* in_sizes, int n_in,
                              void* d_out, int out_size, void* d_ws, size_t ws_size,
                              hipStream_t stream)
{
    (void)in_sizes; (void)n_in; (void)out_size; (void)ws_size;
    const int*   x      = (const int*)  d_in[0];
    const int*   len    = (const int*)  d_in[1];
    const float* embed  = (const float*)d_in[2];
    const float* Wih_e  = (const float*)d_in[3];
    const float* Whh_e  = (const float*)d_in[4];
    const float* bih_e  = (const float*)d_in[5];
    const float* bhh_e  = (const float*)d_in[6];
    const float* Wih_d  = (const float*)d_in[7];
    const float* Whh_d  = (const float*)d_in[8];
    const float* bih_d  = (const float*)d_in[9];
    const float* bhh_d  = (const float*)d_in[10];
    const float* W_lin  = (const float*)d_in[11];
    const float* b_lin  = (const float*)d_in[12];
    float* out = (float*)d_out;

    float* ws = (float*)d_ws;
    size_t off = 0;
    auto alloc = [&](size_t n){ size_t o = off; off += (n + 63) & ~(size_t)63; return o; };
    float* xs   = ws + alloc((size_t)SEQ*BSZ*IPAD);   // 9,961,472
    float* Pe   = ws + alloc((size_t)G4*IPAD);        // 1,245,184
    float* Pd   = ws + alloc((size_t)G4*IPAD);
    float* be   = ws + alloc(G4);
    float* bd   = ws + alloc(G4);
    float* h    = ws + alloc(BH);
    float* c    = ws + alloc(BH);
    float* hat  = ws + alloc(BH);
    float* Gm   = ws + alloc((size_t)BSZ*G4);         // 2,097,152
    float* enc  = ws + alloc((size_t)SEQ*BH);         // 33,554,432
    float* part = ws + alloc(64*64);
    float* wbuf = ws + alloc(64);

    // setup
    embed_gather_k<<<dim3(SEQ, BSZ), 64, 0, stream>>>(x, embed, xs);
    pad_w_k<<<dim3(G4, 2), 64, 0, stream>>>(Wih_e, Wih_d, Pe, Pd);
    bias_comb_k<<<32, 256, 0, stream>>>(bih_e, bhh_e, bih_d, bhh_d, be, bd);
    zero_hc_k<<<BH/256, 256, 0, stream>>>(h, c);

    dim3 ggrid(G4/BN, BSZ/BM);   // (32, 8)

    // encoder forward
    for (int t = 0; t < SEQ; ++t){
        lstm_gemm_k<<<ggrid, 256, 0, stream>>>(xs + (size_t)t*BSZ*IPAD, IPAD, Pe,
                                               h, HDIM, Whh_e, be, Gm);
        lstm_gates_k<<<BH/256, 256, 0, stream>>>(Gm, c, h, nullptr, enc + (size_t)t*BH, 0);
    }
    // encoder backward (continues carry), combine in place: enc[k] = 0.5*(enc[k] + h_bwd_k)
    for (int k = 0; k < SEQ; ++k){
        lstm_gemm_k<<<ggrid, 256, 0, stream>>>(xs + (size_t)(SEQ-1-k)*BSZ*IPAD, IPAD, Pe,
                                               h, HDIM, Whh_e, be, Gm);
        lstm_gates_k<<<BH/256, 256, 0, stream>>>(Gm, c, h, enc + (size_t)k*BH, enc + (size_t)k*BH, 1);
    }
    // decoder
    for (int t = 0; t < SEQ; ++t){
        attn_part_k<<<dim3(64, 64), 256, 0, stream>>>(h, enc, part);
        attn_softmax_k<<<1, 64, 0, stream>>>(part, wbuf);
        attn_apply_k<<<BH/256, 256, 0, stream>>>(h, wbuf, enc, hat);
        lstm_gemm_k<<<ggrid, 256, 0, stream>>>(xs + (size_t)t*BSZ*IPAD, IPAD, Pd,
                                               hat, HDIM, Whh_d, bd, Gm);
        lstm_gates_k<<<BH/256, 256, 0, stream>>>(Gm, c, h, nullptr, nullptr, 2);
        dec_linear_k<<<BSZ, 64, 0, stream>>>(h, W_lin, b_lin, len, out, t);
    }
}

// Round 3
// 9881.284 us; speedup vs baseline: 2.8547x; 2.8547x over previous
//
#include <hip/hip_runtime.h>
#include <hip/hip_bf16.h>

#define BSZ 512
#define SEQ 64
#define IDIM 300
#define KP1 320           // input dim padded to multiple of 32
#define HDIM 1024
#define G4 4096
#define BH (BSZ*HDIM)     // 524288

typedef __attribute__((ext_vector_type(8))) short bf16x8;
typedef __attribute__((ext_vector_type(4))) float f32x4;

__device__ __forceinline__ float sigmoidf_(float x){ return 1.f/(1.f+__expf(-x)); }

// ---------------- setup kernels ----------------
__global__ void embed_gather_k(const int* __restrict__ x, const float* __restrict__ embed,
                               __hip_bfloat16* __restrict__ xs){
    int t = blockIdx.x, b = blockIdx.y;
    int ix = x[b*SEQ + t];
    const float* src = embed + (size_t)ix * IDIM;
    __hip_bfloat16* dst = xs + ((size_t)t*BSZ + b) * KP1;
    for (int k = threadIdx.x; k < KP1; k += 64)
        dst[k] = __float2bfloat16(k < IDIM ? src[k] : 0.f);
}

// variants: 0 Wih_e->Pe[4096][320], 1 Wih_d->Pd, 2 Whh_e->He[4096][1024], 3 Whh_d->Hd
__global__ void conv_w_k(const float* __restrict__ Wih_e, const float* __restrict__ Wih_d,
                         const float* __restrict__ Whh_e, const float* __restrict__ Whh_d,
                         __hip_bfloat16* __restrict__ Pe, __hip_bfloat16* __restrict__ Pd,
                         __hip_bfloat16* __restrict__ He, __hip_bfloat16* __restrict__ Hd){
    int n = blockIdx.x, v = blockIdx.y;
    if (v < 2){
        const float* src = v ? Wih_d : Wih_e;
        __hip_bfloat16* dst = v ? Pd : Pe;
        for (int k = threadIdx.x; k < KP1; k += 64)
            dst[(size_t)n*KP1 + k] = __float2bfloat16(k < IDIM ? src[(size_t)n*IDIM + k] : 0.f);
    } else {
        const float* src = (v == 3) ? Whh_d : Whh_e;
        __hip_bfloat16* dst = (v == 3) ? Hd : He;
        for (int k = threadIdx.x; k < HDIM; k += 64)
            dst[(size_t)n*HDIM + k] = __float2bfloat16(src[(size_t)n*HDIM + k]);
    }
}

__global__ void bias_comb_k(const float* __restrict__ a, const float* __restrict__ b2,
                            const float* __restrict__ c2, const float* __restrict__ d2,
                            float* __restrict__ be, float* __restrict__ bd){
    int i = blockIdx.x*256 + threadIdx.x;
    if (i < G4) be[i] = a[i] + b2[i];
    else { int j = i - G4; bd[j] = c2[j] + d2[j]; }
}

__global__ void zero_hc_k(float* __restrict__ h, float* __restrict__ c,
                          __hip_bfloat16* __restrict__ h_bf){
    int idx = blockIdx.x*256 + threadIdx.x;
    h[idx] = 0.f; c[idx] = 0.f; h_bf[idx] = __float2bfloat16(0.f);
}

// ---------------- bf16 MFMA gate GEMM: G = bias + A1@B1^T + A2@B2^T ----------------
// A1:[512][320] bf16, B1:[4096][320] bf16, A2:[512][1024] bf16, B2:[4096][1024] bf16
// G:[512][4096] f32. Block: 64x128 tile, 512 threads (8 waves, 32x32 per wave), BK=32.
#define BM 64
#define BN 128
#define NK1 (KP1/32)      // 10
#define NK2 (HDIM/32)     // 32
#define NKT (NK1+NK2)     // 42

__global__ __launch_bounds__(512) void lstm_gemm_k(
    const __hip_bfloat16* __restrict__ A1, const __hip_bfloat16* __restrict__ B1,
    const __hip_bfloat16* __restrict__ A2, const __hip_bfloat16* __restrict__ B2,
    const float* __restrict__ bias, float* __restrict__ Gm)
{
    __shared__ __align__(16) char lds[2*12288];   // per buf: A 4KB (64r x 64B), B 8KB (128r x 64B)
    const int tid  = threadIdx.x;
    const int lane = tid & 63, wv = tid >> 6;
    const int row0 = blockIdx.y * BM;
    const int col0 = blockIdx.x * BN;
    const int wm = wv >> 2, wn = wv & 3;          // wave sub-tile: rows wm*32, cols wn*32

    f32x4 acc[2][2] = {};

    auto stage = [&](int ks, int p){
        const __hip_bfloat16* A; const __hip_bfloat16* B; int KA, k0;
        if (ks < NK1){ A = A1; B = B1; KA = KP1;  k0 = ks*32; }
        else         { A = A2; B = B2; KA = HDIM; k0 = (ks-NK1)*32; }
        char* base = lds + p*12288;
        if (wv < 4){   // A tile: slots u=tid (0..255), r=u>>2, s=u&3
            int r = tid >> 2, s = tid & 3;
            int g = s ^ ((r >> 1) & 3);                      // inverse swizzle on source
            const __hip_bfloat16* src = A + (size_t)(row0 + r)*KA + k0 + g*8;
            char* dst = base + wv*1024;                      // wave-uniform; lane*16 implicit
            __builtin_amdgcn_global_load_lds(
                (const __attribute__((address_space(1))) void*)src,
                (__attribute__((address_space(3))) void*)dst, 16, 0, 0);
        }
        {   // B tile: slots u=tid (0..511), r=u>>2, s=u&3
            int r = tid >> 2, s = tid & 3;
            int g = s ^ ((r >> 1) & 3);
            const __hip_bfloat16* src = B + (size_t)(col0 + r)*KA + k0 + g*8;
            char* dst = base + 4096 + wv*1024;
            __builtin_amdgcn_global_load_lds(
                (const __attribute__((address_space(1))) void*)src,
                (__attribute__((address_space(3))) void*)dst, 16, 0, 0);
        }
    };

    auto compute = [&](int p){
        const char* Ab = lds + p*12288;
        const char* Bb = Ab + 4096;
        const int rr = lane & 15, g = lane >> 4;
        bf16x8 af[2], bfr[2];
        #pragma unroll
        for (int m = 0; m < 2; ++m){
            int r = wm*32 + m*16 + rr;
            af[m] = *(const bf16x8*)(Ab + r*64 + (g ^ ((r >> 1) & 3))*16);
        }
        #pragma unroll
        for (int n = 0; n < 2; ++n){
            int r = wn*32 + n*16 + rr;
            bfr[n] = *(const bf16x8*)(Bb + r*64 + (g ^ ((r >> 1) & 3))*16);
        }
        #pragma unroll
        for (int m = 0; m < 2; ++m)
            #pragma unroll
            for (int n = 0; n < 2; ++n)
                acc[m][n] = __builtin_amdgcn_mfma_f32_16x16x32_bf16(af[m], bfr[n], acc[m][n], 0, 0, 0);
    };

    stage(0, 0);
    __syncthreads();
    for (int ks = 0; ks < NKT; ++ks){
        int p = ks & 1;
        if (ks + 1 < NKT) stage(ks + 1, p ^ 1);
        compute(p);
        __syncthreads();
    }

    // epilogue: C/D layout col=lane&15, row=(lane>>4)*4+q
    const int rr = lane & 15, q4 = lane >> 4;
    #pragma unroll
    for (int m = 0; m < 2; ++m){
        int grow0 = row0 + wm*32 + m*16 + q4*4;
        #pragma unroll
        for (int n = 0; n < 2; ++n){
            int gcol = col0 + wn*32 + n*16 + rr;
            float bi = bias[gcol];
            #pragma unroll
            for (int q = 0; q < 4; ++q)
                Gm[(size_t)(grow0 + q)*G4 + gcol] = acc[m][n][q] + bi;
        }
    }
}

// ---------------- LSTM pointwise gates ----------------
__global__ __launch_bounds__(256) void lstm_gates_k(
    const float* __restrict__ Gm, float* __restrict__ c, float* __restrict__ h,
    __hip_bfloat16* __restrict__ h_bf,
    const float* __restrict__ extraIn, float* __restrict__ extraOut, int mode)
{
    int idx = blockIdx.x*256 + threadIdx.x;
    int b = idx >> 10, j = idx & 1023;
    const float* g = Gm + (size_t)b*G4;
    float gi = g[j], gf = g[j+HDIM], gg = g[j+2*HDIM], go = g[j+3*HDIM];
    float cc = sigmoidf_(gf)*c[idx] + sigmoidf_(gi)*tanhf(gg);
    float hh = sigmoidf_(go)*tanhf(cc);
    c[idx] = cc; h[idx] = hh; h_bf[idx] = __float2bfloat16(hh);
    if (mode == 0)      extraOut[idx] = hh;
    else if (mode == 1) extraOut[idx] = 0.5f*(extraIn[idx] + hh);
}

// ---------------- attention ----------------
__global__ __launch_bounds__(256) void attn_part_k(
    const float* __restrict__ h, const float* __restrict__ enc, float* __restrict__ part)
{
    int ch = blockIdx.x;   // 64 chunks of 8192
    int s  = blockIdx.y;   // 64 timesteps
    const float* e  = enc + (size_t)s*BH + (size_t)ch*8192;
    const float* hp = h + (size_t)ch*8192;
    float sum = 0.f;
    for (int i = threadIdx.x; i < 8192; i += 256)
        sum += hp[i] * e[i];
    #pragma unroll
    for (int m = 32; m >= 1; m >>= 1) sum += __shfl_xor(sum, m);
    __shared__ float red[4];
    int lane = threadIdx.x & 63, w = threadIdx.x >> 6;
    if (lane == 0) red[w] = sum;
    __syncthreads();
    if (threadIdx.x == 0) part[s*64 + ch] = red[0]+red[1]+red[2]+red[3];
}

// softmax fused into apply; writes hat as bf16 (decoder GEMM input)
__global__ __launch_bounds__(256) void attn_apply_k(
    const float* __restrict__ h, const float* __restrict__ part,
    const float* __restrict__ enc, __hip_bfloat16* __restrict__ hat_bf)
{
    __shared__ float wl[64];
    int lane = threadIdx.x & 63;
    if (threadIdx.x < 64){
        float tot = 0.f;
        #pragma unroll 8
        for (int ch = 0; ch < 64; ++ch) tot += part[lane*64 + ch];
        float m = tot;
        #pragma unroll
        for (int msk = 32; msk >= 1; msk >>= 1) m = fmaxf(m, __shfl_xor(m, msk));
        float e = __expf(tot - m);
        float sm = e;
        #pragma unroll
        for (int msk = 32; msk >= 1; msk >>= 1) sm += __shfl_xor(sm, msk);
        wl[lane] = e / sm;
    }
    __syncthreads();
    size_t idx = (size_t)blockIdx.x*256 + threadIdx.x;
    float v = h[idx];
    #pragma unroll 8
    for (int s = 0; s < SEQ; ++s)
        v += wl[s] * enc[(size_t)s*BH + idx];
    hat_bf[idx] = __float2bfloat16(v);
}

// ---------------- final linear + mask, float32 out ----------------
__global__ void dec_linear_k(const float* __restrict__ h, const float* __restrict__ Wl,
                             const float* __restrict__ bl, const int* __restrict__ len,
                             float* __restrict__ out, int t)
{
    int b = blockIdx.x, lane = threadIdx.x;
    const float* hb = h + (size_t)b*HDIM;
    float s0 = 0.f, s1 = 0.f;
    for (int j = lane; j < HDIM; j += 64){
        float v = hb[j];
        s0 += v * Wl[j];
        s1 += v * Wl[HDIM + j];
    }
    #pragma unroll
    for (int m = 32; m >= 1; m >>= 1){ s0 += __shfl_xor(s0, m); s1 += __shfl_xor(s1, m); }
    if (lane == 0){
        bool valid = t < len[b];
        size_t r = ((size_t)b*SEQ + t)*2;
        out[r]   = valid ? (s0 + bl[0]) : 1.0f;
        out[r+1] = valid ? (s1 + bl[1]) : 0.0f;
    }
}

// ---------------- launch ----------------
extern "C" void kernel_launch(void* const* d_in, const int* in_sizes, int n_in,
                              void* d_out, int out_size, void* d_ws, size_t ws_size,
                              hipStream_t stream)
{
    (void)in_sizes; (void)n_in; (void)out_size; (void)ws_size;
    const int*   x      = (const int*)  d_in[0];
    const int*   len    = (const int*)  d_in[1];
    const float* embed  = (const float*)d_in[2];
    const float* Wih_e  = (const float*)d_in[3];
    const float* Whh_e  = (const float*)d_in[4];
    const float* bih_e  = (const float*)d_in[5];
    const float* bhh_e  = (const float*)d_in[6];
    const float* Wih_d  = (const float*)d_in[7];
    const float* Whh_d  = (const float*)d_in[8];
    const float* bih_d  = (const float*)d_in[9];
    const float* bhh_d  = (const float*)d_in[10];
    const float* W_lin  = (const float*)d_in[11];
    const float* b_lin  = (const float*)d_in[12];
    float* out = (float*)d_out;

    float* ws = (float*)d_ws;
    size_t off = 0;
    auto alloc = [&](size_t nfloats){ size_t o = off; off += (nfloats + 63) & ~(size_t)63; return o; };
    __hip_bfloat16* xs_bf  = (__hip_bfloat16*)(ws + alloc((size_t)SEQ*BSZ*KP1/2));
    __hip_bfloat16* Pe     = (__hip_bfloat16*)(ws + alloc((size_t)G4*KP1/2));
    __hip_bfloat16* Pd     = (__hip_bfloat16*)(ws + alloc((size_t)G4*KP1/2));
    __hip_bfloat16* He     = (__hip_bfloat16*)(ws + alloc((size_t)G4*HDIM/2));
    __hip_bfloat16* Hd     = (__hip_bfloat16*)(ws + alloc((size_t)G4*HDIM/2));
    float* be   = ws + alloc(G4);
    float* bd   = ws + alloc(G4);
    float* h    = ws + alloc(BH);
    float* c    = ws + alloc(BH);
    __hip_bfloat16* h_bf   = (__hip_bfloat16*)(ws + alloc(BH/2));
    __hip_bfloat16* hat_bf = (__hip_bfloat16*)(ws + alloc(BH/2));
    float* Gm   = ws + alloc((size_t)BSZ*G4);
    float* enc  = ws + alloc((size_t)SEQ*BH);
    float* part = ws + alloc(64*64);

    embed_gather_k<<<dim3(SEQ, BSZ), 64, 0, stream>>>(x, embed, xs_bf);
    conv_w_k<<<dim3(G4, 4), 64, 0, stream>>>(Wih_e, Wih_d, Whh_e, Whh_d, Pe, Pd, He, Hd);
    bias_comb_k<<<32, 256, 0, stream>>>(bih_e, bhh_e, bih_d, bhh_d, be, bd);
    zero_hc_k<<<BH/256, 256, 0, stream>>>(h, c, h_bf);

    dim3 ggrid(G4/BN, BSZ/BM);   // (32, 8) = 256 blocks

    // encoder forward
    for (int t = 0; t < SEQ; ++t){
        lstm_gemm_k<<<ggrid, 512, 0, stream>>>(xs_bf + (size_t)t*BSZ*KP1, Pe, h_bf, He, be, Gm);
        lstm_gates_k<<<BH/256, 256, 0, stream>>>(Gm, c, h, h_bf, nullptr, enc + (size_t)t*BH, 0);
    }
    // encoder backward (same cell, carry continues); combine in place
    for (int k = 0; k < SEQ; ++k){
        lstm_gemm_k<<<ggrid, 512, 0, stream>>>(xs_bf + (size_t)(SEQ-1-k)*BSZ*KP1, Pe, h_bf, He, be, Gm);
        lstm_gates_k<<<BH/256, 256, 0, stream>>>(Gm, c, h, h_bf, enc + (size_t)k*BH, enc + (size_t)k*BH, 1);
    }
    // decoder
    for (int t = 0; t < SEQ; ++t){
        attn_part_k<<<dim3(64, 64), 256, 0, stream>>>(h, enc, part);
        attn_apply_k<<<BH/256, 256, 0, stream>>>(h, part, enc, hat_bf);
        lstm_gemm_k<<<ggrid, 512, 0, stream>>>(xs_bf + (size_t)t*BSZ*KP1, Pd, hat_bf, Hd, bd, Gm);
        lstm_gates_k<<<BH/256, 256, 0, stream>>>(Gm, c, h, h_bf, nullptr, nullptr, 2);
        dec_linear_k<<<BSZ, 64, 0, stream>>>(h, W_lin, b_lin, len, out, t);
    }
}

// Round 4
// 7141.991 us; speedup vs baseline: 3.9496x; 1.3835x over previous
//
#include <hip/hip_runtime.h>
#include <hip/hip_bf16.h>

#define BSZ 512
#define SEQ 64
#define IDIM 300
#define KP1 320           // input dim padded to multiple of 32
#define HDIM 1024
#define G4 4096
#define BH (BSZ*HDIM)     // 524288

typedef __attribute__((ext_vector_type(8))) short bf16x8;
typedef __attribute__((ext_vector_type(4))) float f32x4;
typedef __attribute__((ext_vector_type(8))) unsigned short u16x8;

__device__ __forceinline__ float sigmoidf_(float x){ return 1.f/(1.f+__expf(-x)); }
__device__ __forceinline__ float bf2f(unsigned short u){
    union{unsigned int i; float f;} v; v.i = ((unsigned)u)<<16; return v.f;
}

// ---------------- setup kernels ----------------
__global__ void embed_gather_k(const int* __restrict__ x, const float* __restrict__ embed,
                               __hip_bfloat16* __restrict__ xs){
    int t = blockIdx.x, b = blockIdx.y;
    int ix = x[b*SEQ + t];
    const float* src = embed + (size_t)ix * IDIM;
    __hip_bfloat16* dst = xs + ((size_t)t*BSZ + b) * KP1;
    for (int k = threadIdx.x; k < KP1; k += 64)
        dst[k] = __float2bfloat16(k < IDIM ? src[k] : 0.f);
}

// Repack weights to bf16 with gate-interleaved rows:
// new row nr -> orig row ((nr>>5)&3)*1024 + (nr>>7)*32 + (nr&31)
// so a 128-col GEMM tile holds all 4 gates of 32 hidden units.
__global__ void conv_w_k(const float* __restrict__ Wih_e, const float* __restrict__ Wih_d,
                         const float* __restrict__ Whh_e, const float* __restrict__ Whh_d,
                         __hip_bfloat16* __restrict__ Pe, __hip_bfloat16* __restrict__ Pd,
                         __hip_bfloat16* __restrict__ He, __hip_bfloat16* __restrict__ Hd){
    int nr = blockIdx.x, v = blockIdx.y;
    int orig = ((nr>>5)&3)*HDIM + (nr>>7)*32 + (nr&31);
    if (v < 2){
        const float* src = (v ? Wih_d : Wih_e) + (size_t)orig*IDIM;
        __hip_bfloat16* dst = (v ? Pd : Pe) + (size_t)nr*KP1;
        for (int k = threadIdx.x; k < KP1; k += 64)
            dst[k] = __float2bfloat16(k < IDIM ? src[k] : 0.f);
    } else {
        const float* src = ((v == 3) ? Whh_d : Whh_e) + (size_t)orig*HDIM;
        __hip_bfloat16* dst = ((v == 3) ? Hd : He) + (size_t)nr*HDIM;
        for (int k = threadIdx.x; k < HDIM; k += 64)
            dst[k] = __float2bfloat16(src[k]);
    }
}

__global__ void bias_comb_k(const float* __restrict__ a, const float* __restrict__ b2,
                            const float* __restrict__ c2, const float* __restrict__ d2,
                            float* __restrict__ be, float* __restrict__ bd){
    int i = blockIdx.x*256 + threadIdx.x;       // 8192
    int nr = i & 4095;
    int orig = ((nr>>5)&3)*HDIM + (nr>>7)*32 + (nr&31);
    if (i < G4) be[nr] = a[orig] + b2[orig];
    else        bd[nr] = c2[orig] + d2[orig];
}

__global__ void zero_hc_k(float* __restrict__ h, float* __restrict__ c,
                          __hip_bfloat16* __restrict__ h_bf){
    int idx = blockIdx.x*256 + threadIdx.x;
    h[idx] = 0.f; c[idx] = 0.f; h_bf[idx] = __float2bfloat16(0.f);
}

// ---------------- fused bf16 MFMA GEMM + LSTM cell ----------------
// G = bias + A1@B1^T + A2@B2^T (gate-interleaved cols), then cell update in epilogue.
// mode 0: enc[idx]=bf16(h)   mode 1: enc[idx]=bf16(0.5*(enc[idx]+h))   mode 2: none
#define BM 64
#define BN 128
#define NK1 (KP1/32)      // 10
#define NK2 (HDIM/32)     // 32
#define NKT (NK1+NK2)     // 42

__global__ __launch_bounds__(512) void lstm_step_k(
    const __hip_bfloat16* __restrict__ A1, const __hip_bfloat16* __restrict__ B1,
    const __hip_bfloat16* __restrict__ A2, const __hip_bfloat16* __restrict__ B2,
    const float* __restrict__ bias,
    float* __restrict__ c, float* __restrict__ h, __hip_bfloat16* __restrict__ h_bf,
    __hip_bfloat16* __restrict__ encSlot, int mode)
{
    __shared__ __align__(16) char smem[34048];   // staging 24KB | epilogue 4*64*33*4=33792B
    const int tid  = threadIdx.x;
    const int lane = tid & 63, wv = tid >> 6;
    const int row0 = blockIdx.y * BM;
    const int col0 = blockIdx.x * BN;
    const int wm = wv >> 2, wn = wv & 3;

    f32x4 acc[2][2] = {};

    auto stage = [&](int ks, int p){
        const __hip_bfloat16* A; const __hip_bfloat16* B; int KA, k0;
        if (ks < NK1){ A = A1; B = B1; KA = KP1;  k0 = ks*32; }
        else         { A = A2; B = B2; KA = HDIM; k0 = (ks-NK1)*32; }
        char* base = smem + p*12288;
        if (wv < 4){   // A tile 64r x 64B
            int r = tid >> 2, s = tid & 3;
            int g = s ^ ((r >> 1) & 3);
            const __hip_bfloat16* src = A + (size_t)(row0 + r)*KA + k0 + g*8;
            char* dst = base + wv*1024;
            __builtin_amdgcn_global_load_lds(
                (const __attribute__((address_space(1))) void*)src,
                (__attribute__((address_space(3))) void*)dst, 16, 0, 0);
        }
        {   // B tile 128r x 64B
            int r = tid >> 2, s = tid & 3;
            int g = s ^ ((r >> 1) & 3);
            const __hip_bfloat16* src = B + (size_t)(col0 + r)*KA + k0 + g*8;
            char* dst = base + 4096 + wv*1024;
            __builtin_amdgcn_global_load_lds(
                (const __attribute__((address_space(1))) void*)src,
                (__attribute__((address_space(3))) void*)dst, 16, 0, 0);
        }
    };

    auto compute = [&](int p){
        const char* Ab = smem + p*12288;
        const char* Bb = Ab + 4096;
        const int rr = lane & 15, g = lane >> 4;
        bf16x8 af[2], bfr[2];
        #pragma unroll
        for (int m = 0; m < 2; ++m){
            int r = wm*32 + m*16 + rr;
            af[m] = *(const bf16x8*)(Ab + r*64 + (g ^ ((r >> 1) & 3))*16);
        }
        #pragma unroll
        for (int n = 0; n < 2; ++n){
            int r = wn*32 + n*16 + rr;
            bfr[n] = *(const bf16x8*)(Bb + r*64 + (g ^ ((r >> 1) & 3))*16);
        }
        #pragma unroll
        for (int m = 0; m < 2; ++m)
            #pragma unroll
            for (int n = 0; n < 2; ++n)
                acc[m][n] = __builtin_amdgcn_mfma_f32_16x16x32_bf16(af[m], bfr[n], acc[m][n], 0, 0, 0);
    };

    stage(0, 0);
    __syncthreads();
    for (int ks = 0; ks < NKT; ++ks){
        int p = ks & 1;
        if (ks + 1 < NKT) stage(ks + 1, p ^ 1);
        compute(p);
        __syncthreads();
    }

    // ---- epilogue: exchange gates via LDS, apply LSTM cell ----
    float* ep = (float*)smem;                    // [gate][64][33] floats
    {
        const int rr = lane & 15, q4 = lane >> 4;
        #pragma unroll
        for (int m = 0; m < 2; ++m){
            int row = wm*32 + m*16 + q4*4;
            #pragma unroll
            for (int n = 0; n < 2; ++n){
                int jj = n*16 + rr;
                float bi = bias[col0 + wn*32 + jj];
                #pragma unroll
                for (int q = 0; q < 4; ++q)
                    ep[(wn*64 + row + q)*33 + jj] = acc[m][n][q] + bi;
            }
        }
    }
    __syncthreads();
    {
        int row = tid >> 3;                      // 0..63
        int jj0 = (tid & 7) * 4;
        size_t base = (size_t)(row0 + row)*HDIM + blockIdx.x*32 + jj0;
        #pragma unroll
        for (int e = 0; e < 4; ++e){
            float gi = ep[(0*64 + row)*33 + jj0 + e];
            float gf = ep[(1*64 + row)*33 + jj0 + e];
            float gg = ep[(2*64 + row)*33 + jj0 + e];
            float go = ep[(3*64 + row)*33 + jj0 + e];
            size_t idx = base + e;
            float cc = sigmoidf_(gf)*c[idx] + sigmoidf_(gi)*tanhf(gg);
            float hh = sigmoidf_(go)*tanhf(cc);
            c[idx] = cc; h[idx] = hh; h_bf[idx] = __float2bfloat16(hh);
            if (mode == 0)
                encSlot[idx] = __float2bfloat16(hh);
            else if (mode == 1)
                encSlot[idx] = __float2bfloat16(0.5f*(__bfloat162float(encSlot[idx]) + hh));
        }
    }
}

// ---------------- attention ----------------
__global__ __launch_bounds__(256) void attn_part_k(
    const __hip_bfloat16* __restrict__ h_bf, const __hip_bfloat16* __restrict__ enc,
    float* __restrict__ part)
{
    int ch = blockIdx.x;   // 64 chunks of 8192 elems
    int s  = blockIdx.y;   // 64 timesteps
    const u16x8* e  = (const u16x8*)(enc + (size_t)s*BH + (size_t)ch*8192);
    const u16x8* hp = (const u16x8*)(h_bf + (size_t)ch*8192);
    float sum = 0.f;
    for (int i = threadIdx.x; i < 1024; i += 256){
        u16x8 ev = e[i], hv = hp[i];
        #pragma unroll
        for (int j = 0; j < 8; ++j) sum += bf2f(hv[j]) * bf2f(ev[j]);
    }
    #pragma unroll
    for (int m = 32; m >= 1; m >>= 1) sum += __shfl_xor(sum, m);
    __shared__ float red[4];
    int lane = threadIdx.x & 63, w = threadIdx.x >> 6;
    if (lane == 0) red[w] = sum;
    __syncthreads();
    if (threadIdx.x == 0) part[s*64 + ch] = red[0]+red[1]+red[2]+red[3];
}

// softmax fused; hat written as bf16 (decoder GEMM A2 input)
__global__ __launch_bounds__(256) void attn_apply_k(
    const float* __restrict__ h, const float* __restrict__ part,
    const __hip_bfloat16* __restrict__ enc, __hip_bfloat16* __restrict__ hat_bf)
{
    __shared__ float wl[64];
    int lane = threadIdx.x & 63;
    if (threadIdx.x < 64){
        float tot = 0.f;
        #pragma unroll 8
        for (int ch = 0; ch < 64; ++ch) tot += part[lane*64 + ch];
        float m = tot;
        #pragma unroll
        for (int msk = 32; msk >= 1; msk >>= 1) m = fmaxf(m, __shfl_xor(m, msk));
        float e = __expf(tot - m);
        float sm = e;
        #pragma unroll
        for (int msk = 32; msk >= 1; msk >>= 1) sm += __shfl_xor(sm, msk);
        wl[lane] = e / sm;
    }
    __syncthreads();
    size_t i8 = ((size_t)blockIdx.x*256 + threadIdx.x) * 8;
    float v[8];
    {
        f32x4 a = *(const f32x4*)(h + i8);
        f32x4 b = *(const f32x4*)(h + i8 + 4);
        v[0]=a[0]; v[1]=a[1]; v[2]=a[2]; v[3]=a[3];
        v[4]=b[0]; v[5]=b[1]; v[6]=b[2]; v[7]=b[3];
    }
    for (int s = 0; s < SEQ; ++s){
        u16x8 ev = *(const u16x8*)(enc + (size_t)s*BH + i8);
        float w = wl[s];
        #pragma unroll
        for (int j = 0; j < 8; ++j) v[j] += w * bf2f(ev[j]);
    }
    u16x8 ov;
    #pragma unroll
    for (int j = 0; j < 8; ++j){
        __hip_bfloat16 b = __float2bfloat16(v[j]);
        ov[j] = *(unsigned short*)&b;
    }
    *(u16x8*)(hat_bf + i8) = ov;
}

// ---------------- final linear + mask, float32 out ----------------
__global__ void dec_linear_k(const float* __restrict__ h, const float* __restrict__ Wl,
                             const float* __restrict__ bl, const int* __restrict__ len,
                             float* __restrict__ out, int t)
{
    int b = blockIdx.x, lane = threadIdx.x;
    const float* hb = h + (size_t)b*HDIM;
    float s0 = 0.f, s1 = 0.f;
    for (int j = lane; j < HDIM; j += 64){
        float v = hb[j];
        s0 += v * Wl[j];
        s1 += v * Wl[HDIM + j];
    }
    #pragma unroll
    for (int m = 32; m >= 1; m >>= 1){ s0 += __shfl_xor(s0, m); s1 += __shfl_xor(s1, m); }
    if (lane == 0){
        bool valid = t < len[b];
        size_t r = ((size_t)b*SEQ + t)*2;
        out[r]   = valid ? (s0 + bl[0]) : 1.0f;
        out[r+1] = valid ? (s1 + bl[1]) : 0.0f;
    }
}

// ---------------- launch ----------------
extern "C" void kernel_launch(void* const* d_in, const int* in_sizes, int n_in,
                              void* d_out, int out_size, void* d_ws, size_t ws_size,
                              hipStream_t stream)
{
    (void)in_sizes; (void)n_in; (void)out_size; (void)ws_size;
    const int*   x      = (const int*)  d_in[0];
    const int*   len    = (const int*)  d_in[1];
    const float* embed  = (const float*)d_in[2];
    const float* Wih_e  = (const float*)d_in[3];
    const float* Whh_e  = (const float*)d_in[4];
    const float* bih_e  = (const float*)d_in[5];
    const float* bhh_e  = (const float*)d_in[6];
    const float* Wih_d  = (const float*)d_in[7];
    const float* Whh_d  = (const float*)d_in[8];
    const float* bih_d  = (const float*)d_in[9];
    const float* bhh_d  = (const float*)d_in[10];
    const float* W_lin  = (const float*)d_in[11];
    const float* b_lin  = (const float*)d_in[12];
    float* out = (float*)d_out;

    float* ws = (float*)d_ws;
    size_t off = 0;
    auto alloc = [&](size_t nfloats){ size_t o = off; off += (nfloats + 63) & ~(size_t)63; return o; };
    __hip_bfloat16* xs_bf  = (__hip_bfloat16*)(ws + alloc((size_t)SEQ*BSZ*KP1/2));
    __hip_bfloat16* Pe     = (__hip_bfloat16*)(ws + alloc((size_t)G4*KP1/2));
    __hip_bfloat16* Pd     = (__hip_bfloat16*)(ws + alloc((size_t)G4*KP1/2));
    __hip_bfloat16* He     = (__hip_bfloat16*)(ws + alloc((size_t)G4*HDIM/2));
    __hip_bfloat16* Hd     = (__hip_bfloat16*)(ws + alloc((size_t)G4*HDIM/2));
    float* be   = ws + alloc(G4);
    float* bd   = ws + alloc(G4);
    float* h    = ws + alloc(BH);
    float* c    = ws + alloc(BH);
    __hip_bfloat16* h_bf   = (__hip_bfloat16*)(ws + alloc(BH/2));
    __hip_bfloat16* hat_bf = (__hip_bfloat16*)(ws + alloc(BH/2));
    __hip_bfloat16* enc    = (__hip_bfloat16*)(ws + alloc((size_t)SEQ*BH/2));  // 64 MB
    float* part = ws + alloc(64*64);

    embed_gather_k<<<dim3(SEQ, BSZ), 64, 0, stream>>>(x, embed, xs_bf);
    conv_w_k<<<dim3(G4, 4), 64, 0, stream>>>(Wih_e, Wih_d, Whh_e, Whh_d, Pe, Pd, He, Hd);
    bias_comb_k<<<32, 256, 0, stream>>>(bih_e, bhh_e, bih_d, bhh_d, be, bd);
    zero_hc_k<<<BH/256, 256, 0, stream>>>(h, c, h_bf);

    dim3 ggrid(G4/BN, BSZ/BM);   // (32, 8) = 256 blocks

    // encoder forward
    for (int t = 0; t < SEQ; ++t)
        lstm_step_k<<<ggrid, 512, 0, stream>>>(xs_bf + (size_t)t*BSZ*KP1, Pe, h_bf, He, be,
                                               c, h, h_bf, enc + (size_t)t*BH, 0);
    // encoder backward (carry continues); combine in place
    for (int k = 0; k < SEQ; ++k)
        lstm_step_k<<<ggrid, 512, 0, stream>>>(xs_bf + (size_t)(SEQ-1-k)*BSZ*KP1, Pe, h_bf, He, be,
                                               c, h, h_bf, enc + (size_t)k*BH, 1);
    // decoder
    for (int t = 0; t < SEQ; ++t){
        attn_part_k<<<dim3(64, 64), 256, 0, stream>>>(h_bf, enc, part);
        attn_apply_k<<<256, 256, 0, stream>>>(h, part, enc, hat_bf);
        lstm_step_k<<<ggrid, 512, 0, stream>>>(xs_bf + (size_t)t*BSZ*KP1, Pd, hat_bf, Hd, bd,
                                               c, h, h_bf, nullptr, 2);
        dec_linear_k<<<BSZ, 64, 0, stream>>>(h, W_lin, b_lin, len, out, t);
    }
}